// Round 9
// baseline (247.885 us; speedup 1.0000x reference)
//
#include <hip/hip_runtime.h>
#include <math.h>

#define EMB_D 64
#define EMB_K 1024
#define NROWS 65536            // 64*32*32
#define QELEMS (NROWS * EMB_D) // 4194304

// d_out layout (floats): [0, 4194304) quantized | [4194304] loss | [4194305, ...) indices (as float)
// d_ws layout (bytes):   [0, 262144) Etsw float[65536] | [262144, 266240) esq float[1024]
//                        [266240, 266248) double loss accumulator
//
// Etsw layout (interleaved for SCALAR streaming): code k, dim d lives at
//   Etsw[(k>>3)*512 + (d>>2)*32 + (k&7)*4 + (d&3)]
// i.e. for an 8-code block (512 floats total), each d-chunk j (4 dims) is 32
// contiguous floats -> wave-uniform s_load_dwordx16 pairs in the main loop.
// (Round 7 bug: block stride was 1024 -> 512 KiB footprint, clobbered esq/lsum
//  and overran d_ws. Stride is now 512; total ws footprint = 266248 B.)

// accumulate 4 products into acc, in x/y/z/w order (d-ascending chain,
// identical to all prior rounds -> bit-identical distances)
#define DOT4(acc, q, e)                                    \
    do {                                                   \
        acc = fmaf((q).x, (e).x, acc);                     \
        acc = fmaf((q).y, (e).y, acc);                     \
        acc = fmaf((q).z, (e).z, acc);                     \
        acc = fmaf((q).w, (e).w, acc);                     \
    } while (0)

// ---------------- Kernel A: build Etsw + esq ----------------
// Thread t owns code k. Reads E[d][k] coalesced across t; esq is the same
// d-ascending fmaf chain as rounds 1-6 (must not change: rounding-sensitive).
__global__ __launch_bounds__(256) void prep_kernel(const float* __restrict__ E,
                                                   float* __restrict__ Etsw,
                                                   float* __restrict__ esq,
                                                   double* lsum) {
    const int k = blockIdx.x * 256 + threadIdx.x;
    if (k == 0) *lsum = 0.0;  // ws re-poisoned 0xAA each launch
    float s = 0.f;
    float* dst = Etsw + (size_t)(k >> 3) * 512 + (k & 7) * 4;
#pragma unroll
    for (int j = 0; j < 16; ++j) {
        float4 q;
        q.x = E[(j * 4 + 0) * EMB_K + k];
        q.y = E[(j * 4 + 1) * EMB_K + k];
        q.z = E[(j * 4 + 2) * EMB_K + k];
        q.w = E[(j * 4 + 3) * EMB_K + k];
        s = fmaf(q.x, q.x, s); s = fmaf(q.y, q.y, s);
        s = fmaf(q.z, q.z, s); s = fmaf(q.w, q.w, s);
        *reinterpret_cast<float4*>(dst + j * 32) = q;
    }
    esq[k] = s;
}

// ---------------- Kernel B: fused argmin + quantize + loss ----------------
// Block = 4 waves over the SAME 64 rows (staged in LDS, padded stride 68);
// wave w scans codes [w*256, w*256+256) in 8-code blocks. Per lane only 8
// accumulators + one x-fragment are live (~24 VGPR) -> RA keeps them in
// VGPRs (rounds 3-6 showed it shelves 64-float blocks into AGPRs).
// Codebook + esq stream over the SCALAR pipe (uniform addresses).
__global__ __launch_bounds__(256) void main_kernel(const float* X,
                                                   const float* __restrict__ Etsw,
                                                   const float* __restrict__ esq,
                                                   float* __restrict__ quant,
                                                   float* __restrict__ idxf,
                                                   double* lsum) {
    __shared__ __align__(16) float xs[64 * 68];   // 64 rows, stride 68 dwords (2-way banks only)
    __shared__ float sd[4][64];
    __shared__ int   si[4][64];
    __shared__ int   sidx[64];

    const int tid  = threadIdx.x;
    const int lane = tid & 63;
    const int w    = tid >> 6;
    const int rowbase = blockIdx.x * 64;

    // ---- stage the 64 rows into LDS (coalesced: consecutive tid -> consecutive float4) ----
#pragma unroll
    for (int u = 0; u < 4; ++u) {
        int m = u * 256 + tid;
        int r = m >> 4, j = m & 15;
        float4 v = reinterpret_cast<const float4*>(X)[(size_t)(rowbase + r) * 16 + j];
        *reinterpret_cast<float4*>(&xs[r * 68 + j * 4]) = v;
    }
    __syncthreads();

    const float* xrow = &xs[lane * 68];

    // xsq: same d-ascending chain as before
    float xsq = 0.f;
#pragma unroll
    for (int j = 0; j < 16; ++j) {
        float4 x4 = *reinterpret_cast<const float4*>(xrow + j * 4);
        DOT4(xsq, x4, x4);
    }

    // wave-uniform code-chunk base (readfirstlane => provably uniform => s_load)
    const int k0 = __builtin_amdgcn_readfirstlane(w) * (EMB_K / 4);

    float bestd = INFINITY;
    int   besti = 0;
    for (int b = 0; b < 32; ++b) {                 // 32 blocks of 8 codes
        const int kb = k0 + b * 8;
        const float* eb = Etsw + (size_t)(kb >> 3) * 512;    // uniform
        float a0 = 0.f, a1 = 0.f, a2 = 0.f, a3 = 0.f;
        float a4 = 0.f, a5 = 0.f, a6 = 0.f, a7 = 0.f;
#pragma unroll
        for (int j = 0; j < 16; ++j) {
            const float4 x4 = *reinterpret_cast<const float4*>(xrow + j * 4);
            const float4* ej = reinterpret_cast<const float4*>(eb + j * 32);
            float4 e0 = ej[0], e1 = ej[1], e2 = ej[2], e3 = ej[3];
            float4 e4 = ej[4], e5 = ej[5], e6 = ej[6], e7 = ej[7];
            DOT4(a0, x4, e0); DOT4(a1, x4, e1); DOT4(a2, x4, e2); DOT4(a3, x4, e3);
            DOT4(a4, x4, e4); DOT4(a5, x4, e5); DOT4(a6, x4, e6); DOT4(a7, x4, e7);
        }
        const float* eq = esq + kb;                // uniform -> s_load
        float q0 = (xsq - 2.0f * a0) + eq[0];
        float q1 = (xsq - 2.0f * a1) + eq[1];
        float q2 = (xsq - 2.0f * a2) + eq[2];
        float q3 = (xsq - 2.0f * a3) + eq[3];
        float q4 = (xsq - 2.0f * a4) + eq[4];
        float q5 = (xsq - 2.0f * a5) + eq[5];
        float q6 = (xsq - 2.0f * a6) + eq[6];
        float q7 = (xsq - 2.0f * a7) + eq[7];
        // strict '<', ascending k: first index wins on ties (reference argmax(-d))
        if (q0 < bestd) { bestd = q0; besti = kb + 0; }
        if (q1 < bestd) { bestd = q1; besti = kb + 1; }
        if (q2 < bestd) { bestd = q2; besti = kb + 2; }
        if (q3 < bestd) { bestd = q3; besti = kb + 3; }
        if (q4 < bestd) { bestd = q4; besti = kb + 4; }
        if (q5 < bestd) { bestd = q5; besti = kb + 5; }
        if (q6 < bestd) { bestd = q6; besti = kb + 6; }
        if (q7 < bestd) { bestd = q7; besti = kb + 7; }
    }
    sd[w][lane] = bestd;
    si[w][lane] = besti;
    __syncthreads();

    // ---- combine the 4 k-chunks (ascending w keeps lowest index on ties) ----
    if (tid < 64) {
        float bd = sd[0][lane];
        int   bi = si[0][lane];
#pragma unroll
        for (int u = 1; u < 4; ++u) {
            if (sd[u][lane] < bd) { bd = sd[u][lane]; bi = si[u][lane]; }
        }
        sidx[lane] = bi;
        idxf[rowbase + lane] = (float)bi;
    }
    __syncthreads();

    // ---- fused quantize + loss: thread t handles row t>>2, quarter t&3 ----
    // x comes from the LDS stage (saves a global re-read); q gathered from Etsw.
    {
        const int r = tid >> 2;
        const int p = tid & 3;
        const int k = sidx[r];
        const float* xrp = &xs[r * 68 + p * 16];
        const float* qb  = Etsw + (size_t)(k >> 3) * 512 + (k & 7) * 4;
        float4* oq = reinterpret_cast<float4*>(quant + (size_t)(rowbase + r) * EMB_D) + p * 4;
        float ps = 0.f;
#pragma unroll
        for (int u = 0; u < 4; ++u) {
            int j = p * 4 + u;
            float4 xx = *reinterpret_cast<const float4*>(xrp + u * 4);
            float4 q  = *reinterpret_cast<const float4*>(qb + j * 32);
            float dx = q.x - xx.x, dy = q.y - xx.y, dz = q.z - xx.z, dw = q.w - xx.w;
            oq[u] = make_float4(xx.x + dx, xx.y + dy, xx.z + dz, xx.w + dw);
            ps += dx * dx + dy * dy + dz * dz + dw * dw;
        }
#pragma unroll
        for (int off = 32; off > 0; off >>= 1) ps += __shfl_down(ps, off, 64);
        if (lane == 0) atomicAdd(lsum, (double)ps);
    }
}

// ---------------- Kernel D: finalize loss ----------------
__global__ void finalize_kernel(const double* lsum, float* loss_out) {
    double m = *lsum / (double)QELEMS;
    *loss_out = (float)(m + 0.25 * m);  // e_latent + BETA * q_latent (same value)
}

extern "C" void kernel_launch(void* const* d_in, const int* in_sizes, int n_in,
                              void* d_out, int out_size, void* d_ws, size_t ws_size,
                              hipStream_t stream) {
    const float* X = (const float*)d_in[0];   // [64,32,32,64] = 4194304 floats
    const float* E = (const float*)d_in[1];   // [64,1024]     = 65536 floats

    float* out = (float*)d_out;
    float* quant = out;                  // [0, 4194304)
    float* loss  = out + QELEMS;         // [4194304]
    float* idxf  = out + QELEMS + 1;     // [4194305, ...)

    char* ws = (char*)d_ws;
    float*  Etsw = (float*)(ws);             // 256 KiB (interleaved layout, stride 512/8-code block)
    float*  esq  = (float*)(ws + 262144);    // 4 KiB
    double* lsum = (double*)(ws + 266240);   // 8 B

    prep_kernel<<<EMB_K / 256, 256, 0, stream>>>(E, Etsw, esq, lsum);
    main_kernel<<<NROWS / 64, 256, 0, stream>>>(X, Etsw, esq, quant, idxf, lsum);
    finalize_kernel<<<1, 1, 0, stream>>>(lsum, loss);
}